// Round 1
// 270.534 us; speedup vs baseline: 1.0968x; 1.0968x over previous
//
#include <hip/hip_runtime.h>
#include <hip/hip_bf16.h>
#include <math.h>

#define IN_F  256
#define OUT_F 64
#define PD    264      // w_t row stride in bf16 elems (264*2=528B: min-time b128 frag reads)

typedef __attribute__((ext_vector_type(8))) short bf16x8;
typedef __attribute__((ext_vector_type(4))) float f32x4;

__device__ inline unsigned short f2b(float x) {
    union { __hip_bfloat16 h; unsigned short u; } cv;
    cv.h = __float2bfloat16(x);
    return cv.u;
}
__device__ inline float b2f_lo(unsigned int u) { return __uint_as_float(u << 16); }
__device__ inline float b2f_hi(unsigned int u) { return __uint_as_float(u & 0xffff0000u); }

// ---------------------------------------------------------------------------
// K1: fused  (a) sup_bf = bf16(tanh(feat @ w))  and  (b) CSR row_ptr build.
//
// gemm part: blocks [0, GB): 512 threads = 8 waves, each wave owns ONE 16-node
// m-tile (vs 4 before). Grid 391->782 blocks and 8 waves share one 33KB LDS
// allocation -> occupancy 12.5% -> ~50%+ (was the measured bottleneck:
// MfmaUtil 1.8, VALUBusy 9.6, both starved). kt loop fully unrolled so all 16
// A-loads issue up front.
//
// rowptr part: blocks [GB, GB+RB): edge-parallel (thread e writes
// row_ptr[rows[e]+1 .. rows[e+1]] = e+1), replacing the latency-bound
// binary-search-per-row kernel; hides under the gemm blocks.
// ---------------------------------------------------------------------------
__global__ __launch_bounds__(512) void gemm_rowptr_kernel(
    const float* __restrict__ feat,      // [N, 256]
    const float* __restrict__ w,         // [256, 64]
    const int*  __restrict__ active,     // [1]
    const int*  __restrict__ rows,       // [E] sorted
    unsigned short* __restrict__ sup_bf, // [N, 64] bf16 bits
    int* __restrict__ row_ptr,           // [N+1] or null
    int N, int E, int GB)
{
    __shared__ unsigned short wt[OUT_F * PD];   // 33792 B, wt[n*PD + k]

    if ((int)blockIdx.x >= GB) {
        // -------- edge-parallel row_ptr --------
        int e = ((int)blockIdx.x - GB) * 512 + (int)threadIdx.x;
        if (e < E) {
            int r  = rows[e];
            int rn = (e + 1 < E) ? rows[e + 1] : N;
            if (e == 0) {
                for (int j = 0; j <= r; ++j) row_ptr[j] = 0;
            }
            for (int j = r + 1; j <= rn; ++j) row_ptr[j] = e + 1;
        }
        return;   // block-uniform branch: no barrier divergence
    }

    const int t = threadIdx.x;
    // stage weight: fp32 [k][n] -> bf16 transposed [n][k]
    #pragma unroll
    for (int r = 0; r < 8; ++r) {
        int f = r * 512 + t;              // float4 index, 0..4095
        float4 v = ((const float4*)w)[f];
        int k = f >> 4;                   // 4f/64
        int n = (f & 15) << 2;            // 4f%64
        wt[(n + 0) * PD + k] = f2b(v.x);
        wt[(n + 1) * PD + k] = f2b(v.y);
        wt[(n + 2) * PD + k] = f2b(v.z);
        wt[(n + 3) * PD + k] = f2b(v.w);
    }
    __syncthreads();

    const int lane = t & 63;
    const int m    = lane & 15;
    const int quad = lane >> 4;
    const int node0 = (int)blockIdx.x * 128 + (t >> 6) * 16;   // wave's m-tile

    int nd = node0 + m;
    if (nd > N - 1) nd = N - 1;           // clamp; OOB rows never stored
    const float* arow = feat + (size_t)nd * IN_F;

    f32x4 acc[4];                         // 4 n-tiles
    #pragma unroll
    for (int b = 0; b < 4; ++b) acc[b] = (f32x4)0.0f;

    #pragma unroll
    for (int kt = 0; kt < 8; ++kt) {
        const int ko = kt * 32 + quad * 8;
        f32x4 lo = *(const f32x4*)(arow + ko);
        f32x4 hi = *(const f32x4*)(arow + ko + 4);
        bf16x8 a;
        a[0] = (short)f2b(lo[0]); a[1] = (short)f2b(lo[1]);
        a[2] = (short)f2b(lo[2]); a[3] = (short)f2b(lo[3]);
        a[4] = (short)f2b(hi[0]); a[5] = (short)f2b(hi[1]);
        a[6] = (short)f2b(hi[2]); a[7] = (short)f2b(hi[3]);
        #pragma unroll
        for (int nt = 0; nt < 4; ++nt) {
            bf16x8 b = *(const bf16x8*)(&wt[(nt * 16 + m) * PD + ko]);
            acc[nt] = __builtin_amdgcn_mfma_f32_16x16x32_bf16(a, b, acc[nt], 0, 0, 0);
        }
    }

    int act = __builtin_amdgcn_readfirstlane(active[0]);
    #pragma unroll
    for (int r = 0; r < 4; ++r) {
        int node = node0 + quad * 4 + r;   // C/D: col=lane&15, row=quad*4+reg
        if (node >= N) continue;
        #pragma unroll
        for (int nt = 0; nt < 4; ++nt) {
            float v = acc[nt][r];
            if (act) v = tanhf(v);
            sup_bf[(size_t)node * OUT_F + nt * 16 + m] = f2b(v);
        }
    }
}

// ---------------------------------------------------------------------------
// SpMM: out[r,:] = sum_e vals[e] * x[cols[e],:]
//
// Wave per row; 8 lanes per edge (part = lane&7 reads 16B of the 128B bf16
// row). One dwordx4 gather instruction = 8 edges x 128B = 1KB in flight
// (vs 256B before). Main loop = 16 edges (2 batches) per latency exposure;
// tail = one masked dual-batch covering up to 15 edges. Mean degree 16 ->
// 1-2 gather exposures per row instead of ~4. 8 accumulators/lane; stride-8
// butterfly (xor 8/16/32) once per row. fp32 outputs are never re-read ->
// nontemporal stores keep the gather table cache-resident.
// ---------------------------------------------------------------------------
__device__ inline int lower_bound(const int* __restrict__ a, int n, int key) {
    int lo = 0, hi = n;
    while (lo < hi) {
        int mid = (lo + hi) >> 1;
        if (a[mid] < key) lo = mid + 1; else hi = mid;
    }
    return lo;
}

__device__ __forceinline__ void fma8b(float v, uint4 g, float* acc) {
    acc[0] = fmaf(v, b2f_lo(g.x), acc[0]); acc[1] = fmaf(v, b2f_hi(g.x), acc[1]);
    acc[2] = fmaf(v, b2f_lo(g.y), acc[2]); acc[3] = fmaf(v, b2f_hi(g.y), acc[3]);
    acc[4] = fmaf(v, b2f_lo(g.z), acc[4]); acc[5] = fmaf(v, b2f_hi(g.z), acc[5]);
    acc[6] = fmaf(v, b2f_lo(g.w), acc[6]); acc[7] = fmaf(v, b2f_hi(g.w), acc[7]);
}
__device__ __forceinline__ void fma8f(float v, float4 lo, float4 hi, float* acc) {
    acc[0] = fmaf(v, lo.x, acc[0]); acc[1] = fmaf(v, lo.y, acc[1]);
    acc[2] = fmaf(v, lo.z, acc[2]); acc[3] = fmaf(v, lo.w, acc[3]);
    acc[4] = fmaf(v, hi.x, acc[4]); acc[5] = fmaf(v, hi.y, acc[5]);
    acc[6] = fmaf(v, hi.z, acc[6]); acc[7] = fmaf(v, hi.w, acc[7]);
}

template <bool XBF>
__global__ __launch_bounds__(256) void spmm_kernel(
    const int* __restrict__ row_ptr,          // [N+1] or null
    const int* __restrict__ rows,             // [E] sorted (fallback)
    const int* __restrict__ cols,             // [E]
    const float* __restrict__ vals,           // [E]
    const void* __restrict__ x,               // [N,64] bf16 or fp32
    float* __restrict__ out,                  // [N,64] fp32
    unsigned short* __restrict__ out_bf,      // [N,64] bf16 or null
    int N, int E)
{
    const int row  = blockIdx.x * 4 + (threadIdx.x >> 6);
    const int lane = threadIdx.x & 63;
    const int part = lane & 7;      // which 8-col chunk of the 64-col row
    const int esl  = lane >> 3;     // edge slot 0..7 within a batch
    if (row >= N) return;

    int s, e;
    if (row_ptr) { s = row_ptr[row]; e = row_ptr[row + 1]; }
    else         { s = lower_bound(rows, E, row); e = lower_bound(rows, E, row + 1); }

    const unsigned short* xb = (const unsigned short*)x;
    const float*          xf = (const float*)x;

    float acc[8] = {0.f, 0.f, 0.f, 0.f, 0.f, 0.f, 0.f, 0.f};

    int i = s;
    for (; i + 16 <= e; i += 16) {
        int   ea = i + esl,  eb = i + 8 + esl;
        int   ca = cols[ea], cb = cols[eb];
        float va = vals[ea], vb = vals[eb];
        if (XBF) {
            uint4 ga = *(const uint4*)(xb + (size_t)ca * OUT_F + part * 8);
            uint4 gb = *(const uint4*)(xb + (size_t)cb * OUT_F + part * 8);
            fma8b(va, ga, acc);
            fma8b(vb, gb, acc);
        } else {
            const float* pa = xf + (size_t)ca * OUT_F + part * 8;
            const float* pb = xf + (size_t)cb * OUT_F + part * 8;
            float4 la = *(const float4*)pa, ha = *(const float4*)(pa + 4);
            float4 lb = *(const float4*)pb, hb = *(const float4*)(pb + 4);
            fma8f(va, la, ha, acc);
            fma8f(vb, lb, hb, acc);
        }
    }
    if (i < e) {    // masked dual batch: covers remaining 1..15 edges
        int   ea = i + esl, eb = i + 8 + esl;
        float va = 0.f, vb = 0.f;
        if (XBF) {
            uint4 ga = make_uint4(0u, 0u, 0u, 0u);
            uint4 gb = make_uint4(0u, 0u, 0u, 0u);
            if (ea < e) { int c = cols[ea]; va = vals[ea];
                          ga = *(const uint4*)(xb + (size_t)c * OUT_F + part * 8); }
            if (eb < e) { int c = cols[eb]; vb = vals[eb];
                          gb = *(const uint4*)(xb + (size_t)c * OUT_F + part * 8); }
            fma8b(va, ga, acc);
            fma8b(vb, gb, acc);
        } else {
            float4 la = make_float4(0.f,0.f,0.f,0.f), ha = la, lb = la, hb = la;
            if (ea < e) { int c = cols[ea]; va = vals[ea];
                          const float* p = xf + (size_t)c * OUT_F + part * 8;
                          la = *(const float4*)p; ha = *(const float4*)(p + 4); }
            if (eb < e) { int c = cols[eb]; vb = vals[eb];
                          const float* p = xf + (size_t)c * OUT_F + part * 8;
                          lb = *(const float4*)p; hb = *(const float4*)(p + 4); }
            fma8f(va, la, ha, acc);
            fma8f(vb, lb, hb, acc);
        }
    }

    // reduce across the 8 edge slots (lanes part, part+8, ..., part+56)
    #pragma unroll
    for (int j = 0; j < 8; ++j) {
        acc[j] += __shfl_xor(acc[j], 8, 64);
        acc[j] += __shfl_xor(acc[j], 16, 64);
        acc[j] += __shfl_xor(acc[j], 32, 64);
    }

    if (esl == 0) {
        size_t base = (size_t)row * OUT_F + part * 8;
        f32x4 o0 = {acc[0], acc[1], acc[2], acc[3]};
        f32x4 o1 = {acc[4], acc[5], acc[6], acc[7]};
        __builtin_nontemporal_store(o0, (f32x4*)(out + base));      // never re-read
        __builtin_nontemporal_store(o1, (f32x4*)(out + base + 4));
        if (out_bf) {   // re-read by spmm2's gathers: keep cached
            uint4 pk;
            pk.x = (unsigned)f2b(acc[0]) | ((unsigned)f2b(acc[1]) << 16);
            pk.y = (unsigned)f2b(acc[2]) | ((unsigned)f2b(acc[3]) << 16);
            pk.z = (unsigned)f2b(acc[4]) | ((unsigned)f2b(acc[5]) << 16);
            pk.w = (unsigned)f2b(acc[6]) | ((unsigned)f2b(acc[7]) << 16);
            *(uint4*)(out_bf + base) = pk;
        }
    }
}

// ---------------------------------------------------------------------------
extern "C" void kernel_launch(void* const* d_in, const int* in_sizes, int n_in,
                              void* d_out, int out_size, void* d_ws, size_t ws_size,
                              hipStream_t stream) {
    const float* feat   = (const float*)d_in[0];   // [N,256] fp32
    const float* w      = (const float*)d_in[1];   // [256,64] fp32
    const int*   rows   = (const int*)d_in[2];     // [E] sorted
    const int*   cols   = (const int*)d_in[3];     // [E]
    const float* vals   = (const float*)d_in[4];   // [E] fp32
    const int*   active = (const int*)d_in[5];     // [1]

    const int N = in_sizes[0] / IN_F;   // 100000
    const int E = in_sizes[2];          // 1600000

    float* out = (float*)d_out;                    // [output | az] fp32
    float* az  = out + (size_t)N * OUT_F;

    // Workspace tiers
    size_t rp_bytes = (((size_t)(N + 1) * sizeof(int)) + 255) & ~(size_t)255;
    size_t bf_bytes = (((size_t)N * OUT_F * sizeof(unsigned short)) + 255) & ~(size_t)255;
    char* ws = (char*)d_ws;

    int* row_ptr = (ws_size >= rp_bytes) ? (int*)ws : nullptr;
    size_t used = row_ptr ? rp_bytes : 0;

    unsigned short* sup_bf;
    unsigned short* mid_bf = nullptr;   // bf16 copy of `output` for spmm2 gather
    if (ws_size >= used + 2 * bf_bytes) {
        sup_bf = (unsigned short*)(ws + used);
        mid_bf = (unsigned short*)(ws + used + bf_bytes);
    } else if (ws_size >= used + bf_bytes) {
        sup_bf = (unsigned short*)(ws + used);
    } else {
        // az half of d_out as bf16 scratch (dead before spmm2 writes az)
        sup_bf = (unsigned short*)az;
    }

    {   // fused: sup_bf = bf16(tanh(feat @ w))  +  row_ptr build
        int GB = (N + 127) / 128;
        int RB = row_ptr ? (E + 511) / 512 : 0;
        gemm_rowptr_kernel<<<GB + RB, 512, 0, stream>>>(
            feat, w, active, rows, sup_bf, row_ptr, N, E, GB);
    }

    int spmm_blocks = (N + 3) / 4;
    // output = A @ support   (gather bf16; also emit bf16 copy if we have room)
    spmm_kernel<true><<<spmm_blocks, 256, 0, stream>>>(
        row_ptr, rows, cols, vals, sup_bf, out, mid_bf, N, E);
    // az = A @ output
    if (mid_bf) {
        spmm_kernel<true><<<spmm_blocks, 256, 0, stream>>>(
            row_ptr, rows, cols, vals, mid_bf, az, nullptr, N, E);
    } else {
        spmm_kernel<false><<<spmm_blocks, 256, 0, stream>>>(
            row_ptr, rows, cols, vals, out, az, nullptr, N, E);
    }
}

// Round 3
// 264.027 us; speedup vs baseline: 1.1238x; 1.0246x over previous
//
#include <hip/hip_runtime.h>
#include <hip/hip_bf16.h>
#include <math.h>

#define IN_F  256
#define OUT_F 64
#define PD    264      // w_t row stride in bf16 elems (264*2=528B: min-time b128 frag reads)

typedef __attribute__((ext_vector_type(8))) short bf16x8;
typedef __attribute__((ext_vector_type(4))) float f32x4;
typedef __attribute__((ext_vector_type(2))) float f32x2;

__device__ inline unsigned short f2b(float x) {
    union { __hip_bfloat16 h; unsigned short u; } cv;
    cv.h = __float2bfloat16(x);
    return cv.u;
}
__device__ inline float b2f_lo(unsigned int u) { return __uint_as_float(u << 16); }
__device__ inline float b2f_hi(unsigned int u) { return __uint_as_float(u & 0xffff0000u); }

// ---------------------------------------------------------------------------
// K1: fused  (a) sup_bf = bf16(tanh(feat @ w))  and  (b) CSR row_ptr build.
//
// gemm blocks [0,GB): 512 thr = 8 waves, wave owns one 16-node m-tile.
// feat reads are a 102 MB one-shot stream -> nontemporal loads so they don't
// evict the sup_bf table the following spmm gathers from L2/LLC.
// rowptr blocks [GB,GB+RB): edge-parallel scatter of row starts.
// ---------------------------------------------------------------------------
__global__ __launch_bounds__(512) void gemm_rowptr_kernel(
    const float* __restrict__ feat,      // [N, 256]
    const float* __restrict__ w,         // [256, 64]
    const int*  __restrict__ active,     // [1]
    const int*  __restrict__ rows,       // [E] sorted
    unsigned short* __restrict__ sup_bf, // [N, 64] bf16 bits
    int* __restrict__ row_ptr,           // [N+1] or null
    int N, int E, int GB)
{
    __shared__ unsigned short wt[OUT_F * PD];   // 33792 B, wt[n*PD + k]

    if ((int)blockIdx.x >= GB) {
        // -------- edge-parallel row_ptr --------
        int e = ((int)blockIdx.x - GB) * 512 + (int)threadIdx.x;
        if (e < E) {
            int r  = rows[e];
            int rn = (e + 1 < E) ? rows[e + 1] : N;
            if (e == 0) {
                for (int j = 0; j <= r; ++j) row_ptr[j] = 0;
            }
            for (int j = r + 1; j <= rn; ++j) row_ptr[j] = e + 1;
        }
        return;   // block-uniform branch: no barrier divergence
    }

    const int t = threadIdx.x;
    // stage weight: fp32 [k][n] -> bf16 transposed [n][k]
    #pragma unroll
    for (int r = 0; r < 8; ++r) {
        int f = r * 512 + t;              // float4 index, 0..4095
        float4 v = ((const float4*)w)[f];
        int k = f >> 4;                   // 4f/64
        int n = (f & 15) << 2;            // 4f%64
        wt[(n + 0) * PD + k] = f2b(v.x);
        wt[(n + 1) * PD + k] = f2b(v.y);
        wt[(n + 2) * PD + k] = f2b(v.z);
        wt[(n + 3) * PD + k] = f2b(v.w);
    }
    __syncthreads();

    const int lane = t & 63;
    const int m    = lane & 15;
    const int quad = lane >> 4;
    const int node0 = (int)blockIdx.x * 128 + (t >> 6) * 16;   // wave's m-tile

    int nd = node0 + m;
    if (nd > N - 1) nd = N - 1;           // clamp; OOB rows never stored
    const float* arow = feat + (size_t)nd * IN_F;

    f32x4 acc[4];                         // 4 n-tiles
    #pragma unroll
    for (int b = 0; b < 4; ++b) acc[b] = (f32x4)0.0f;

    #pragma unroll
    for (int kt = 0; kt < 8; ++kt) {
        const int ko = kt * 32 + quad * 8;
        f32x4 lo = __builtin_nontemporal_load((const f32x4*)(arow + ko));
        f32x4 hi = __builtin_nontemporal_load((const f32x4*)(arow + ko + 4));
        bf16x8 a;
        a[0] = (short)f2b(lo[0]); a[1] = (short)f2b(lo[1]);
        a[2] = (short)f2b(lo[2]); a[3] = (short)f2b(lo[3]);
        a[4] = (short)f2b(hi[0]); a[5] = (short)f2b(hi[1]);
        a[6] = (short)f2b(hi[2]); a[7] = (short)f2b(hi[3]);
        #pragma unroll
        for (int nt = 0; nt < 4; ++nt) {
            bf16x8 b = *(const bf16x8*)(&wt[(nt * 16 + m) * PD + ko]);
            acc[nt] = __builtin_amdgcn_mfma_f32_16x16x32_bf16(a, b, acc[nt], 0, 0, 0);
        }
    }

    int act = __builtin_amdgcn_readfirstlane(active[0]);
    #pragma unroll
    for (int r = 0; r < 4; ++r) {
        int node = node0 + quad * 4 + r;   // C/D: col=lane&15, row=quad*4+reg
        if (node >= N) continue;
        #pragma unroll
        for (int nt = 0; nt < 4; ++nt) {
            float v = acc[nt][r];
            if (act) v = tanhf(v);
            sup_bf[(size_t)node * OUT_F + nt * 16 + m] = f2b(v);
        }
    }
}

// ---------------------------------------------------------------------------
// SpMM: out[r,:] = sum_e vals[e] * x[cols[e],:]
//
// Two rows per wave: each 32-lane half owns one row, lane owns cols {2l,2l+1}
// -> acc[2], ZERO cross-lane shuffles (round-0's butterfly was a long serial
// tail per row). Per 16-edge batch: all 32 metadata loads hoisted
// (uniform-per-half address, clamped + value-masked -> no tail code), then
// all 16 gathers issued independently (16 random 128B segments in
// flight/wave), then the FMA chain. Critical path per row: meta -> gather ->
// fma = 2 latency exposures. Stores stay coalesced: 32 lanes x float2 = 256B.
// ---------------------------------------------------------------------------
__device__ inline int lower_bound(const int* __restrict__ a, int n, int key) {
    int lo = 0, hi = n;
    while (lo < hi) {
        int mid = (lo + hi) >> 1;
        if (a[mid] < key) lo = mid + 1; else hi = mid;
    }
    return lo;
}

template <bool XBF>
__global__ __launch_bounds__(256) void spmm_kernel(
    const int* __restrict__ row_ptr,          // [N+1] or null
    const int* __restrict__ rows,             // [E] sorted (fallback)
    const int* __restrict__ cols,             // [E]
    const float* __restrict__ vals,           // [E]
    const void* __restrict__ x,               // [N,64] bf16 or fp32
    float* __restrict__ out,                  // [N,64] fp32
    unsigned short* __restrict__ out_bf,      // [N,64] bf16 or null
    int N, int E)
{
    const int lane = threadIdx.x & 63;
    const int h    = lane >> 5;       // half -> which of the wave's 2 rows
    const int l    = lane & 31;       // lane in half -> cols {2l, 2l+1}
    const int row  = blockIdx.x * 8 + (threadIdx.x >> 6) * 2 + h;

    const bool valid = row < N;
    const int  rc    = valid ? row : N - 1;

    int s, e;
    if (row_ptr) { s = row_ptr[rc]; e = row_ptr[rc + 1]; }
    else         { s = lower_bound(rows, E, rc); e = lower_bound(rows, E, rc + 1); }
    if (!valid) e = s;

    const unsigned short* xb = (const unsigned short*)x;
    const float*          xf = (const float*)x;

    float a0 = 0.0f, a1 = 0.0f;

    for (int base = s; base < e; base += 16) {
        // ---- batch metadata: 32 independent loads, clamped + masked ----
        int   c[16];
        float v[16];
        #pragma unroll
        for (int j = 0; j < 16; ++j) {
            int idx = base + j;
            int cl  = idx < e ? idx : e - 1;    // e > base >= s here, so e-1 valid
            c[j] = cols[cl];
            v[j] = (idx < e) ? vals[cl] : 0.0f;
        }
        // ---- 16 independent gathers, then FMA chain ----
        if (XBF) {
            #pragma unroll
            for (int j = 0; j < 16; ++j) {
                unsigned int g = *(const unsigned int*)(xb + (size_t)c[j] * OUT_F + 2 * l);
                a0 = fmaf(v[j], b2f_lo(g), a0);
                a1 = fmaf(v[j], b2f_hi(g), a1);
            }
        } else {
            #pragma unroll
            for (int j = 0; j < 16; ++j) {
                float2 g = *(const float2*)(xf + (size_t)c[j] * OUT_F + 2 * l);
                a0 = fmaf(v[j], g.x, a0);
                a1 = fmaf(v[j], g.y, a1);
            }
        }
    }

    if (valid) {
        size_t bidx = (size_t)row * OUT_F + 2 * l;
        f32x2 o = {a0, a1};
        __builtin_nontemporal_store(o, (f32x2*)(out + bidx));  // fp32 never gathered
        if (out_bf) {   // re-read by spmm2's gathers: keep cached
            unsigned int pk = (unsigned int)f2b(a0) | ((unsigned int)f2b(a1) << 16);
            *(unsigned int*)(out_bf + bidx) = pk;
        }
    }
}

// ---------------------------------------------------------------------------
extern "C" void kernel_launch(void* const* d_in, const int* in_sizes, int n_in,
                              void* d_out, int out_size, void* d_ws, size_t ws_size,
                              hipStream_t stream) {
    const float* feat   = (const float*)d_in[0];   // [N,256] fp32
    const float* w      = (const float*)d_in[1];   // [256,64] fp32
    const int*   rows   = (const int*)d_in[2];     // [E] sorted
    const int*   cols   = (const int*)d_in[3];     // [E]
    const float* vals   = (const float*)d_in[4];   // [E] fp32
    const int*   active = (const int*)d_in[5];     // [1]

    const int N = in_sizes[0] / IN_F;   // 100000
    const int E = in_sizes[2];          // 1600000

    float* out = (float*)d_out;                    // [output | az] fp32
    float* az  = out + (size_t)N * OUT_F;

    // Workspace tiers
    size_t rp_bytes = (((size_t)(N + 1) * sizeof(int)) + 255) & ~(size_t)255;
    size_t bf_bytes = (((size_t)N * OUT_F * sizeof(unsigned short)) + 255) & ~(size_t)255;
    char* ws = (char*)d_ws;

    int* row_ptr = (ws_size >= rp_bytes) ? (int*)ws : nullptr;
    size_t used = row_ptr ? rp_bytes : 0;

    unsigned short* sup_bf;
    unsigned short* mid_bf = nullptr;   // bf16 copy of `output` for spmm2 gather
    if (ws_size >= used + 2 * bf_bytes) {
        sup_bf = (unsigned short*)(ws + used);
        mid_bf = (unsigned short*)(ws + used + bf_bytes);
    } else if (ws_size >= used + bf_bytes) {
        sup_bf = (unsigned short*)(ws + used);
    } else {
        // az half of d_out as bf16 scratch (dead before spmm2 writes az)
        sup_bf = (unsigned short*)az;
    }

    {   // fused: sup_bf = bf16(tanh(feat @ w))  +  row_ptr build
        int GB = (N + 127) / 128;
        int RB = row_ptr ? (E + 511) / 512 : 0;
        gemm_rowptr_kernel<<<GB + RB, 512, 0, stream>>>(
            feat, w, active, rows, sup_bf, row_ptr, N, E, GB);
    }

    int spmm_blocks = (N + 7) / 8;   // 8 rows per 256-thread block (2 per wave)
    // output = A @ support   (gather bf16; also emit bf16 copy if we have room)
    spmm_kernel<true><<<spmm_blocks, 256, 0, stream>>>(
        row_ptr, rows, cols, vals, sup_bf, out, mid_bf, N, E);
    // az = A @ output
    if (mid_bf) {
        spmm_kernel<true><<<spmm_blocks, 256, 0, stream>>>(
            row_ptr, rows, cols, vals, mid_bf, az, nullptr, N, E);
    } else {
        spmm_kernel<false><<<spmm_blocks, 256, 0, stream>>>(
            row_ptr, rows, cols, vals, out, az, nullptr, N, E);
    }
}